// Round 6
// baseline (357.248 us; speedup 1.0000x reference)
//
#include <hip/hip_runtime.h>
#include <hip/hip_bf16.h>
#include <hip/hip_cooperative_groups.h>
#include <math.h>

namespace cg = cooperative_groups;

#define D 300
#define R 5
#define NE 1000000
#define B 32
#define NG 25000
#define NS 25000
#define NROWS 50000
#define NBLK 1563      // head-gemm 32-row tiles
#define KU 1808        // padded K for U/Mt (113 * 16)
#define NST 113        // K steps of 16
#define GRID 512

typedef __bf16 bf16x8 __attribute__((ext_vector_type(8)));
typedef float f32x16 __attribute__((ext_vector_type(16)));

// ws layout (floats):
//   wsum [0, 48000)  wcnt [48000, 48160)  hcf [48160, 57760)
//   pm2  float2 at 57760  (64 x 1563)            -> [57760, 257824)
//   U    bf16 [32][1808]  at 257824               -> [257824, 286752)
//   Mt   bf16 [320][1808] at 286752               -> [286752, 576032)

__device__ __forceinline__ void online_upd(float& m, float& s, float v) {
    if (v > m) { s = s * __expf(m - v) + 1.0f; m = v; }
    else       { s += __expf(v - m); }
}
__device__ __forceinline__ void online_merge(float& m, float& s, float om, float os) {
    float M = fmaxf(m, om);
    s = s * __expf(m - M) + os * __expf(om - M);
    m = M;
}

__global__ __launch_bounds__(256, 2) void mono(
    const float* __restrict__ x, const int* __restrict__ ei, const int* __restrict__ et,
    const int* __restrict__ cur, const float* __restrict__ basis, const float* __restrict__ comp,
    const float* __restrict__ root, const float* __restrict__ bias,
    const float* __restrict__ wg, const float* __restrict__ bg,
    const float* __restrict__ wsn, const float* __restrict__ bsn,
    float* __restrict__ out, float* __restrict__ wsum, float* __restrict__ wcnt,
    float* __restrict__ hcf, __bf16* __restrict__ U, __bf16* __restrict__ Mt,
    float2* __restrict__ pm2)
{
    cg::grid_group grid = cg::this_grid();
    const int tid = threadIdx.x;
    const int bid = blockIdx.x;
    const int gid = bid * 256 + tid;
    const int wid = tid >> 6, l = tid & 63, lm = l & 31, lh = l >> 5;

    __shared__ unsigned int tbl[32];
    __shared__ int curl[B];
    __shared__ int lcnt;
    __shared__ int2 loc[64];
    __shared__ float tile[32][33];
    __shared__ __bf16 hcbL[32 * 304];
    __shared__ float red_m[4], red_s[4], lseS;

    // ---- P0: zero wsum|wcnt|hcf (57760 floats contiguous) ----
    if (gid < 14440) ((float4*)wsum)[gid] = float4{0.f, 0.f, 0.f, 0.f};
    grid.sync();

    // ---- P1: edge scan+accum (2 chunks/block) + Mt transpose + U x-part ----
    for (int pass = 0; pass < 2; ++pass) {
        if (tid < 32) tbl[tid] = 0u;
        if (tid == 0) lcnt = 0;
        __syncthreads();
        if (tid < B) { int c = cur[tid]; curl[tid] = c; atomicOr(&tbl[(c >> 5) & 31], 1u << (c & 31)); }
        __syncthreads();
        long base = ((long)(bid + GRID * pass) * 256 + tid) * 4;
        if (base < NE) {
            int ds4[4];
            if (base + 4 <= NE) {
                int4 d4 = *(const int4*)(ei + NE + base);
                ds4[0] = d4.x; ds4[1] = d4.y; ds4[2] = d4.z; ds4[3] = d4.w;
            } else {
                for (int k = 0; k < 4; ++k) ds4[k] = (base + k < NE) ? ei[NE + base + k] : -1;
            }
            #pragma unroll
            for (int k = 0; k < 4; ++k) {
                int dst = ds4[k];
                if (dst < 0) continue;
                if (!(tbl[(dst >> 5) & 31] & (1u << (dst & 31)))) continue;  // bloom reject
                int e = (int)base + k;
                int r = -1, src = 0;
                for (int b = 0; b < B; ++b) {
                    if (dst == curl[b]) {
                        if (r < 0) { r = et[e]; src = ei[e]; }
                        atomicAdd(&wcnt[b * R + r], 1.0f);
                        int p = atomicAdd(&lcnt, 1);
                        if (p < 64) loc[p] = int2{src, b * R + r};
                    }
                }
            }
        }
        __syncthreads();
        int n = lcnt; if (n > 64) n = 64;
        for (int m = 0; m < n; ++m) {
            int2 pr = loc[m];
            const float* xs = x + (long)pr.x * D;
            float* sm = wsum + (long)pr.y * D;
            for (int t = tid; t < D; t += 256) atomicAdd(&sm[t], xs[t]);
        }
        __syncthreads();
    }
    for (int u = bid; u < 602; u += GRID) {
        if (u < 570) {  // Mt transpose tile: k0 x e0, 32x32
            int kt = u / 10, et2 = u - kt * 10;
            int k0 = kt * 32, e0 = et2 * 32;
            for (int rr = tid >> 5; rr < 32; rr += 8) {
                int k = k0 + rr, e = e0 + (tid & 31);
                float v = 0.f;
                if (k < 1800 && e < D) {
                    const float* Mrow = (k < D) ? (root + (long)k * D) : (basis + (long)(k - D) * D);
                    v = Mrow[e];
                }
                tile[rr][tid & 31] = v;
            }
            __syncthreads();
            for (int rr = tid >> 5; rr < 32; rr += 8) {
                int e = e0 + rr, k = k0 + (tid & 31);
                if (k < KU) Mt[(long)e * KU + k] = (__bf16)tile[tid & 31][rr];
            }
        } else {        // U x-part row b + K-pad zeros
            int b = u - 570;
            int node = cur[b];
            for (int k = tid; k < D; k += 256) U[(long)b * KU + k] = (__bf16)x[(long)node * D + k];
            if (tid < 8) U[(long)b * KU + 1800 + tid] = (__bf16)0.f;
        }
        __syncthreads();
    }
    grid.sync();

    // ---- P2: U mc-part (32 x 1500 elems, one per thread) ----
    if (gid < 48000) {
        int b = gid / 1500, g = gid - b * 1500;
        int bb = g / 300, t0 = g - bb * 300;
        float a = 0.f;
        #pragma unroll
        for (int r = 0; r < R; ++r) {
            float inv = 1.0f / fmaxf(wcnt[b * R + r], 1.0f);
            a = fmaf(comp[r * R + bb] * inv, wsum[(long)(b * R + r) * D + t0], a);
        }
        U[(long)b * KU + 300 + g] = (__bf16)a;
    }
    grid.sync();

    // ---- P2b: RGCN MFMA, C[e][b] tiles (10 e-tiles x 15 k-chunks = 150 waves) ----
    {
        int gw = bid * 4 + wid;
        if (gw < 150) {
            int et2 = gw / 15, kc = gw - et2 * 15;
            int s0 = kc * 8, s1 = s0 + 8; if (s1 > NST) s1 = NST;
            const __bf16* arow = Mt + (long)(et2 * 32 + lm) * KU + lh * 8;  // A row = e
            const __bf16* brow = U + (long)lm * KU + lh * 8;                // B col = b
            f32x16 acc = {};
            for (int s = s0; s < s1; ++s)
                acc = __builtin_amdgcn_mfma_f32_32x32x16_bf16(
                    *(const bf16x8*)(arow + 16 * s), *(const bf16x8*)(brow + 16 * s), acc, 0, 0, 0);
            #pragma unroll
            for (int r = 0; r < 16; ++r) {
                int e2 = et2 * 32 + (r & 3) + 8 * (r >> 2) + 4 * lh;
                if (e2 < D) atomicAdd(&hcf[lm * D + e2], acc[r]);
            }
        }
    }
    grid.sync();

    // ---- P3: head GEMM (hc staged to LDS once per block; 1563 wave-tiles) ----
    {
        for (int b2 = 0; b2 < 32; ++b2) {
            for (int kk = tid; kk < 304; kk += 256) {
                float v = 0.f;
                if (kk < D) v = fmaxf(hcf[b2 * D + kk] + bias[kk], 0.f);
                hcbL[b2 * 304 + kk] = (__bf16)v;
            }
        }
        __syncthreads();
        int gw = bid * 4 + wid;
        if (gw < NBLK) {
            bf16x8 bfrag[19];
            const __bf16* hrow = hcbL + lm * 304 + lh * 8;
            #pragma unroll
            for (int s = 0; s < 19; ++s) bfrag[s] = *(const bf16x8*)(hrow + 16 * s);

            int j0 = gw * 32;
            int row = j0 + lm; if (row >= NROWS) row = NROWS - 1;
            const float* wrow = ((row < NG) ? (wg + (long)row * D) : (wsn + (long)(row - NG) * D)) + lh * 8;

            f32x16 acc = {};
            #pragma unroll
            for (int s = 0; s < 18; ++s) {
                float4 w0 = *(const float4*)(wrow + 16 * s);
                float4 w1 = *(const float4*)(wrow + 16 * s + 4);
                bf16x8 a;
                a[0]=(__bf16)w0.x; a[1]=(__bf16)w0.y; a[2]=(__bf16)w0.z; a[3]=(__bf16)w0.w;
                a[4]=(__bf16)w1.x; a[5]=(__bf16)w1.y; a[6]=(__bf16)w1.z; a[7]=(__bf16)w1.w;
                acc = __builtin_amdgcn_mfma_f32_32x32x16_bf16(a, bfrag[s], acc, 0, 0, 0);
            }
            {   // tail: k=288..299 valid; lh=1 loads base+296, upper half zero
                float4 w0 = *(const float4*)(wrow + 288);
                float4 w1 = (lh == 0) ? *(const float4*)(wrow + 292) : float4{0.f, 0.f, 0.f, 0.f};
                bf16x8 a;
                a[0]=(__bf16)w0.x; a[1]=(__bf16)w0.y; a[2]=(__bf16)w0.z; a[3]=(__bf16)w0.w;
                a[4]=(__bf16)w1.x; a[5]=(__bf16)w1.y; a[6]=(__bf16)w1.z; a[7]=(__bf16)w1.w;
                acc = __builtin_amdgcn_mfma_f32_32x32x16_bf16(a, bfrag[18], acc, 0, 0, 0);
            }
            float m0 = -3.0e38f, sm0 = 0.f, m1 = -3.0e38f, sm1 = 0.f;
            #pragma unroll
            for (int r = 0; r < 16; ++r) {
                int j = j0 + (r & 3) + 8 * (r >> 2) + 4 * lh;
                if (j >= NROWS) continue;
                float bv = (j < NG) ? bg[j] : bsn[j - NG];
                float v = acc[r] + bv;
                float* op = (j < NG) ? (out + (long)lm * NG + j)
                                     : (out + (long)B * NG + (long)lm * NS + (j - NG));
                *op = v;
                if (j < NG) online_upd(m0, sm0, v); else online_upd(m1, sm1, v);
            }
            float om0 = __shfl_xor(m0, 32), os0 = __shfl_xor(sm0, 32);
            float om1 = __shfl_xor(m1, 32), os1 = __shfl_xor(sm1, 32);
            online_merge(m0, sm0, om0, os0);
            online_merge(m1, sm1, om1, os1);
            if (lh == 0) {
                pm2[(long)lm * NBLK + gw]       = float2{m0, sm0};
                pm2[(long)(B + lm) * NBLK + gw] = float2{m1, sm1};
            }
        }
    }
    grid.sync();

    // ---- P4: per-row lse reduce + subtract (1600 units) ----
    for (int u = bid; u < 1600; u += GRID) {
        int rw = u / 25, c = u - rw * 25;
        const float2* pr = pm2 + (long)rw * NBLK;
        float m = -3.0e38f, s = 0.f;
        for (int i = tid; i < NBLK; i += 256) { float2 e2 = pr[i]; online_merge(m, s, e2.x, e2.y); }
        #pragma unroll
        for (int o = 32; o; o >>= 1) {
            float om = __shfl_xor(m, o), os = __shfl_xor(s, o);
            online_merge(m, s, om, os);
        }
        if ((tid & 63) == 0) { red_m[tid >> 6] = m; red_s[tid >> 6] = s; }
        __syncthreads();
        if (tid == 0) {
            float M = red_m[0], S = red_s[0];
            for (int w = 1; w < 4; ++w) online_merge(M, S, red_m[w], red_s[w]);
            lseS = M + __logf(S);
        }
        __syncthreads();
        float lse = lseS;
        float4* o4 = (float4*)out + (long)rw * 6250 + c * 250;
        if (tid < 250) { float4 v = o4[tid]; v.x -= lse; v.y -= lse; v.z -= lse; v.w -= lse; o4[tid] = v; }
        __syncthreads();
    }
}

extern "C" void kernel_launch(void* const* d_in, const int* in_sizes, int n_in,
                              void* d_out, int out_size, void* d_ws, size_t ws_size,
                              hipStream_t stream) {
    const float* x     = (const float*)d_in[0];
    const int*   ei    = (const int*)d_in[1];
    const int*   et    = (const int*)d_in[2];
    const int*   cur   = (const int*)d_in[3];
    const float* basis = (const float*)d_in[4];
    const float* comp  = (const float*)d_in[5];
    const float* root  = (const float*)d_in[6];
    const float* bias  = (const float*)d_in[7];
    const float* wg    = (const float*)d_in[8];
    const float* bgl   = (const float*)d_in[9];
    const float* wsn   = (const float*)d_in[10];
    const float* bsn   = (const float*)d_in[11];
    float* out  = (float*)d_out;
    float* wsf  = (float*)d_ws;
    float*  wsum_p = wsf;                          // [0, 48000)
    float*  wcnt_p = wsf + 48000;                  // [48000, 48160)
    float*  hcf_p  = wsf + 48160;                  // [48160, 57760)
    float2* pm2_p  = (float2*)(wsf + 57760);       // 64 x 1563 float2
    __bf16* U_p    = (__bf16*)(wsf + 257824);      // 32 x 1808 bf16
    __bf16* Mt_p   = (__bf16*)(wsf + 286752);      // 320 x 1808 bf16

    void* args[19] = { (void*)&x, (void*)&ei, (void*)&et, (void*)&cur, (void*)&basis,
                       (void*)&comp, (void*)&root, (void*)&bias, (void*)&wg, (void*)&bgl,
                       (void*)&wsn, (void*)&bsn, (void*)&out, (void*)&wsum_p, (void*)&wcnt_p,
                       (void*)&hcf_p, (void*)&U_p, (void*)&Mt_p, (void*)&pm2_p };
    hipLaunchCooperativeKernel((const void*)mono, dim3(GRID), dim3(256), args, 0, stream);
}

// Round 7
// 73.937 us; speedup vs baseline: 4.8318x; 4.8318x over previous
//
#include <hip/hip_runtime.h>
#include <hip/hip_bf16.h>
#include <math.h>

#define D 300
#define R 5
#define NE 1000000
#define B 32
#define NG 25000
#define NS 25000
#define NROWS 50000
#define NBLK 1563      // 32-row head tiles

typedef __bf16 bf16x8 __attribute__((ext_vector_type(8)));
typedef float f32x16 __attribute__((ext_vector_type(16)));

// ws layout (floats):
//   wsum [0, 48000)   wcnt [48000, 48160)   hcf [48160, 57760)
//   pm2  float2 at 57760 (64 rows x 1563 tiles)  -> [57760, 257824)
//   lse  [257824, 257888)

__device__ __forceinline__ void online_upd(float& m, float& s, float v) {
    if (v > m) { s = s * __expf(m - v) + 1.0f; m = v; }
    else       { s += __expf(v - m); }
}
__device__ __forceinline__ void online_merge(float& m, float& s, float om, float os) {
    float M = fmaxf(m, om);
    s = s * __expf(m - M) + os * __expf(om - M);
    m = M;
}

__global__ void zero_ws(float4* __restrict__ p) {
    int i = blockIdx.x * 256 + threadIdx.x;
    if (i < 14440) p[i] = float4{0.f, 0.f, 0.f, 0.f};  // wsum|wcnt|hcf
}

// Fused scan + accumulate (proven R5): bloom dst, compact to LDS, coalesced row-adds.
__global__ __launch_bounds__(256) void scan_accum(
        const int* __restrict__ ei, const int* __restrict__ et,
        const int* __restrict__ cur, const float* __restrict__ x,
        float* __restrict__ wsum, float* __restrict__ wcnt) {
    __shared__ unsigned int tbl[32];
    __shared__ int curl[B];
    __shared__ int lcnt;
    __shared__ int2 loc[64];
    int tid = threadIdx.x;
    if (tid < 32) tbl[tid] = 0u;
    if (tid == 0) lcnt = 0;
    __syncthreads();
    if (tid < B) { int c = cur[tid]; curl[tid] = c; atomicOr(&tbl[(c >> 5) & 31], 1u << (c & 31)); }
    __syncthreads();
    long base = ((long)blockIdx.x * 256 + tid) * 4;
    if (base < NE) {
        int ds4[4];
        if (base + 4 <= NE) {
            int4 d4 = *(const int4*)(ei + NE + base);
            ds4[0] = d4.x; ds4[1] = d4.y; ds4[2] = d4.z; ds4[3] = d4.w;
        } else {
            for (int k = 0; k < 4; ++k) ds4[k] = (base + k < NE) ? ei[NE + base + k] : -1;
        }
        #pragma unroll
        for (int k = 0; k < 4; ++k) {
            int dst = ds4[k];
            if (dst < 0) continue;
            if (!(tbl[(dst >> 5) & 31] & (1u << (dst & 31)))) continue;
            int e = (int)base + k;
            int r = -1, src = 0;
            for (int b = 0; b < B; ++b) {
                if (dst == curl[b]) {
                    if (r < 0) { r = et[e]; src = ei[e]; }
                    atomicAdd(&wcnt[b * R + r], 1.0f);
                    int p = atomicAdd(&lcnt, 1);
                    if (p < 64) loc[p] = int2{src, b * R + r};
                }
            }
        }
    }
    __syncthreads();
    int n = lcnt; if (n > 64) n = 64;
    for (int m = 0; m < n; ++m) {
        int2 pr = loc[m];
        const float* xs = x + (long)pr.x * D;
        float* sm = wsum + (long)pr.y * D;
        for (int t = tid; t < D; t += 256) atomicAdd(&sm[t], xs[t]);
    }
}

// RGCN transform: 72 blocks x 25-row K-chunk of U[32x1800] @ M[1800x300],
// U slice built inline (x rows or comp-folded means), atomic accumulate into hcf.
__global__ __launch_bounds__(320) void rgcn_hc(
        const float* __restrict__ x, const int* __restrict__ cur,
        const float* __restrict__ comp, const float* __restrict__ root,
        const float* __restrict__ basis, const float* __restrict__ wsum,
        const float* __restrict__ wcnt, float* __restrict__ hcf) {
    int kc = blockIdx.x, t = threadIdx.x;
    __shared__ float uL[800];       // 32 b x 25 k
    __shared__ float inv[B * R];
    __shared__ float cmp[R * R];
    if (t < B * R) inv[t] = 1.0f / fmaxf(wcnt[t], 1.0f);
    if (t >= 160 && t < 160 + R * R) cmp[t - 160] = comp[t - 160];
    __syncthreads();
    int d0 = kc * 25;
    if (d0 < 300) {
        for (int i = t; i < 800; i += 320) {
            int b = i / 25, dd = i - b * 25;
            uL[i] = x[(long)cur[b] * D + d0 + dd];
        }
    } else {
        int g0 = d0 - 300;
        int bb = g0 / 300, t0 = g0 - bb * 300;   // 25 | 300, no straddle
        for (int i = t; i < 800; i += 320) {
            int b = i / 25, dd = i - b * 25;
            float a = 0.f;
            #pragma unroll
            for (int r = 0; r < R; ++r)
                a = fmaf(cmp[r * R + bb] * inv[b * R + r], wsum[(long)(b * R + r) * D + t0 + dd], a);
            uL[i] = a;
        }
    }
    __syncthreads();
    if (t < D) {
        const float* Mb = (d0 < 300) ? (root + (long)d0 * D) : (basis + (long)(d0 - 300) * D);
        float acc[B] = {};
        #pragma unroll 5
        for (int i = 0; i < 25; ++i) {
            float m = Mb[(long)i * D + t];
            #pragma unroll
            for (int b = 0; b < B; ++b) acc[b] = fmaf(uL[b * 25 + i], m, acc[b]);
        }
        for (int b = 0; b < B; ++b) atomicAdd(&hcf[b * D + t], acc[b]);
    }
}

// Head GEMM: 256-thread block = 4 wave-tiles of 32 rows; hc staged once per block
// (bias+relu+bf16 inline from hcf). Epilogue: online (m,s) partials -> pm2[row][tile].
__global__ __launch_bounds__(256) void head_gemm_mfma(
    const float* __restrict__ hcf, const float* __restrict__ bias,
    const float* __restrict__ wg, const float* __restrict__ bg,
    const float* __restrict__ wsn, const float* __restrict__ bsn,
    float* __restrict__ out, float2* __restrict__ pm2) {
    __shared__ __bf16 hcbL[32 * 304];
    int tid = threadIdx.x;
    for (int i = tid; i < 32 * 304; i += 256) {
        int b = i / 304, kk = i - b * 304;
        float v = 0.f;
        if (kk < D) v = fmaxf(hcf[b * D + kk] + bias[kk], 0.f);
        hcbL[i] = (__bf16)v;
    }
    __syncthreads();
    int wid = tid >> 6, l = tid & 63, lm = l & 31, lh = l >> 5;
    int tile = blockIdx.x * 4 + wid;
    if (tile >= NBLK) return;

    bf16x8 bfrag[19];
    const __bf16* hrow = hcbL + lm * 304 + lh * 8;
    #pragma unroll
    for (int s = 0; s < 19; ++s) bfrag[s] = *(const bf16x8*)(hrow + 16 * s);

    int j0 = tile * 32;
    int row = j0 + lm; if (row >= NROWS) row = NROWS - 1;
    const float* wrow = ((row < NG) ? (wg + (long)row * D) : (wsn + (long)(row - NG) * D)) + lh * 8;

    f32x16 acc = {};
    #pragma unroll
    for (int s = 0; s < 18; ++s) {
        float4 w0 = *(const float4*)(wrow + 16 * s);
        float4 w1 = *(const float4*)(wrow + 16 * s + 4);
        bf16x8 a;
        a[0]=(__bf16)w0.x; a[1]=(__bf16)w0.y; a[2]=(__bf16)w0.z; a[3]=(__bf16)w0.w;
        a[4]=(__bf16)w1.x; a[5]=(__bf16)w1.y; a[6]=(__bf16)w1.z; a[7]=(__bf16)w1.w;
        acc = __builtin_amdgcn_mfma_f32_32x32x16_bf16(a, bfrag[s], acc, 0, 0, 0);
    }
    {   // tail: k 288..299 valid; lh=1 w0 covers 296..299, upper half zero
        float4 w0 = *(const float4*)(wrow + 288);
        float4 w1 = (lh == 0) ? *(const float4*)(wrow + 292) : float4{0.f, 0.f, 0.f, 0.f};
        bf16x8 a;
        a[0]=(__bf16)w0.x; a[1]=(__bf16)w0.y; a[2]=(__bf16)w0.z; a[3]=(__bf16)w0.w;
        a[4]=(__bf16)w1.x; a[5]=(__bf16)w1.y; a[6]=(__bf16)w1.z; a[7]=(__bf16)w1.w;
        acc = __builtin_amdgcn_mfma_f32_32x32x16_bf16(a, bfrag[18], acc, 0, 0, 0);
    }

    int b = lm;
    float m0 = -3.0e38f, s0 = 0.f, m1 = -3.0e38f, s1 = 0.f;
    #pragma unroll
    for (int r = 0; r < 16; ++r) {
        int j = j0 + (r & 3) + 8 * (r >> 2) + 4 * lh;
        if (j >= NROWS) continue;
        float bv = (j < NG) ? bg[j] : bsn[j - NG];
        float v = acc[r] + bv;
        float* op = (j < NG) ? (out + (long)b * NG + j)
                             : (out + (long)B * NG + (long)b * NS + (j - NG));
        *op = v;
        if (j < NG) online_upd(m0, s0, v); else online_upd(m1, s1, v);
    }
    float om0 = __shfl_xor(m0, 32), os0 = __shfl_xor(s0, 32);
    float om1 = __shfl_xor(m1, 32), os1 = __shfl_xor(s1, 32);
    online_merge(m0, s0, om0, os0);
    online_merge(m1, s1, om1, os1);
    if (lh == 0) {
        pm2[(long)b * NBLK + tile]       = float2{m0, s0};
        pm2[(long)(B + b) * NBLK + tile] = float2{m1, s1};
    }
}

// One block per output row: reduce its 1563-tile strip once -> lse[row].
__global__ __launch_bounds__(256) void lse_red(const float2* __restrict__ pm2,
                                               float* __restrict__ lse) {
    int rw = blockIdx.x, tid = threadIdx.x;
    const float2* pr = pm2 + (long)rw * NBLK;
    float m = -3.0e38f, s = 0.f;
    for (int i = tid; i < NBLK; i += 256) { float2 e = pr[i]; online_merge(m, s, e.x, e.y); }
    #pragma unroll
    for (int o = 32; o; o >>= 1) {
        float om = __shfl_xor(m, o), os = __shfl_xor(s, o);
        online_merge(m, s, om, os);
    }
    __shared__ float sm[4], ss[4];
    if ((tid & 63) == 0) { sm[tid >> 6] = m; ss[tid >> 6] = s; }
    __syncthreads();
    if (tid == 0) {
        float M = sm[0], S = ss[0];
        for (int w = 1; w < 4; ++w) online_merge(M, S, sm[w], ss[w]);
        lse[rw] = M + __logf(S);
    }
}

// 1600 blocks: subtract lse over 250-float4 chunks (rows are contiguous: NG==NS).
__global__ __launch_bounds__(256) void sub_lse(float* __restrict__ out,
                                               const float* __restrict__ lse) {
    int rw = blockIdx.x / 25, c = blockIdx.x % 25;
    float l = lse[rw];
    float4* o4 = (float4*)out + (long)rw * 6250 + c * 250;
    int tid = threadIdx.x;
    if (tid < 250) { float4 v = o4[tid]; v.x -= l; v.y -= l; v.z -= l; v.w -= l; o4[tid] = v; }
}

extern "C" void kernel_launch(void* const* d_in, const int* in_sizes, int n_in,
                              void* d_out, int out_size, void* d_ws, size_t ws_size,
                              hipStream_t stream) {
    const float* x     = (const float*)d_in[0];
    const int*   ei    = (const int*)d_in[1];
    const int*   et    = (const int*)d_in[2];
    const int*   cur   = (const int*)d_in[3];
    const float* basis = (const float*)d_in[4];
    const float* comp  = (const float*)d_in[5];
    const float* root  = (const float*)d_in[6];
    const float* bias  = (const float*)d_in[7];
    const float* wg    = (const float*)d_in[8];
    const float* bgl   = (const float*)d_in[9];
    const float* wsn   = (const float*)d_in[10];
    const float* bsn   = (const float*)d_in[11];
    float* out  = (float*)d_out;
    float* wsf  = (float*)d_ws;
    float*  wsum = wsf;                        // [0, 48000)
    float*  wcnt = wsf + 48000;                // [48000, 48160)
    float*  hcf  = wsf + 48160;                // [48160, 57760)
    float2* pm2  = (float2*)(wsf + 57760);     // 64 x 1563
    float*  lse  = wsf + 257824;               // 64

    zero_ws<<<57, 256, 0, stream>>>((float4*)d_ws);
    scan_accum<<<977, 256, 0, stream>>>(ei, et, cur, x, wsum, wcnt);
    rgcn_hc<<<72, 320, 0, stream>>>(x, cur, comp, root, basis, wsum, wcnt, hcf);
    head_gemm_mfma<<<391, 256, 0, stream>>>(hcf, bias, wg, bgl, wsn, bsn, out, pm2);
    lse_red<<<64, 256, 0, stream>>>(pm2, lse);
    sub_lse<<<1600, 256, 0, stream>>>(out, lse);
}